// Round 5
// baseline (205.851 us; speedup 1.0000x reference)
//
#include <hip/hip_runtime.h>
#include <hip/hip_bf16.h>

typedef __bf16 bf16x8 __attribute__((ext_vector_type(8)));
typedef float f32x16 __attribute__((ext_vector_type(16)));
typedef unsigned short ushort_t;

#define NSENT 8192
#define LSEQ  120
#define GBAGS 256
#define WDIM_ 50
#define DFILT 230
#define NCLS  53
#define KSTEPS 12
#define BFRAG_ELEMS (24*256*8)
#define LROWS 130
#define SPB 8                      // sentences per block (8 waves, 512 threads)

// workspace byte offsets
#define OFF_BFRAG 0
#define OFF_WV64  196608
#define OFF_PF1B  (196608 + 10240000)
#define OFF_PF2B  (OFF_PF1B + 2048)
#define OFF_SENT  (OFF_PF2B + 2048)

static __device__ __forceinline__ ushort_t f2bf(float f) {
    unsigned int u = __float_as_uint(f);
    unsigned int lsb = (u >> 16) & 1u;
    u += 0x7fffu + lsb;
    return (ushort_t)(u >> 16);
}

// ---------------- prep 0: Wc -> MFMA B-fragment layout; pf1/pf2 -> bf16 ----------------
__global__ __launch_bounds__(256) void pcnn_prep_b(const float* __restrict__ Wc,
                                                   const float* __restrict__ pf1,
                                                   const float* __restrict__ pf2,
                                                   ushort_t* __restrict__ Bfrag,
                                                   ushort_t* __restrict__ pf1b,
                                                   ushort_t* __restrict__ pf2b) {
    int idx = blockIdx.x * 256 + threadIdx.x;
    if (idx < 1010) pf1b[idx] = f2bf(pf1[idx]);
    else if (idx < 2020) pf2b[idx - 1010] = f2bf(pf2[idx - 1010]);
    if (idx >= BFRAG_ELEMS) return;
    int c   = idx >> 11;
    int rem = idx & 2047;
    int d   = rem >> 3;
    int j   = rem & 7;
    int k   = c * 8 + j;
    int dh  = k >> 6;
    int w   = k & 63;
    float val = (d < DFILT && w < 60) ? Wc[(d * 3 + dh) * 60 + w] : 0.0f;
    Bfrag[idx] = f2bf(val);
}

// ---------------- prep 1: Wv (80000x50 fp32) -> Wv64 (80000x64 bf16, zero-padded) --------
__global__ __launch_bounds__(256) void pcnn_prep_wv(const float* __restrict__ Wv,
                                                    ushort_t* __restrict__ Wv64) {
    int idx = blockIdx.x * 256 + threadIdx.x;   // 5,120,000 total
    int r = idx >> 6, k = idx & 63;
    float val = (k < WDIM_) ? Wv[r * WDIM_ + k] : 0.0f;
    Wv64[idx] = f2bf(val);
}

// ---------------- staging: load one 16B chunk of one emb row into registers ----------
__device__ __forceinline__ uint4 load_task(int task,
    const int* __restrict__ sx, const int* __restrict__ sld, const int* __restrict__ srd,
    const ushort_t* __restrict__ Wv64, const ushort_t* __restrict__ pf1b,
    const ushort_t* __restrict__ pf2b) {
    int l = task >> 3, c = task & 7;
    int tok = sx[l];
    if (c < 6) {
        return *reinterpret_cast<const uint4*>(Wv64 + tok * 64 + c * 8);
    } else if (c == 6) {
        int lp = sld[l], rp = srd[l];
        ushort_t u[8];
        *reinterpret_cast<unsigned int*>(&u[0]) =
            *reinterpret_cast<const unsigned int*>(Wv64 + tok * 64 + 48);
        u[2] = pf1b[lp * 5 + 0]; u[3] = pf1b[lp * 5 + 1]; u[4] = pf1b[lp * 5 + 2];
        u[5] = pf1b[lp * 5 + 3]; u[6] = pf1b[lp * 5 + 4];
        u[7] = pf2b[rp * 5 + 0];
        return *reinterpret_cast<const uint4*>(u);
    } else {
        int rp = srd[l];
        ushort_t u[8];
        u[0] = pf2b[rp * 5 + 1]; u[1] = pf2b[rp * 5 + 2];
        u[2] = pf2b[rp * 5 + 3]; u[3] = pf2b[rp * 5 + 4];
        u[4] = 0; u[5] = 0; u[6] = 0; u[7] = 0;
        return *reinterpret_cast<const uint4*>(u);
    }
}

__device__ __forceinline__ void write_task(unsigned char* __restrict__ buf, int task, uint4 v) {
    int l = task >> 3, c = task & 7;
    int byteoff = l * 128 + ((c * 16) ^ ((l & 7) << 4));
    *reinterpret_cast<uint4*>(buf + byteoff) = v;
}

// ---------------- per-wave conv compute: one 32-wide d-tile ----------------
__device__ __forceinline__ void conv_compute(const unsigned char* __restrict__ buf, int n,
    const bf16x8 (&Bf)[KSTEPS], float bcv, float* __restrict__ sent,
    int dcol, int lhalf, int l31) {
    float dmax = -1e30f;
    #pragma unroll
    for (int tt = 0; tt < 4; ++tt) {
        f32x16 acc;
        #pragma unroll
        for (int r = 0; r < 16; ++r) acc[r] = 0.0f;
        int trow = tt * 32 + l31;
        #pragma unroll
        for (int ks = 0; ks < KSTEPS; ++ks) {
            int dh = ks >> 2, q = ks & 3;
            int l = trow + dh;
            int w0 = q * 16 + lhalf * 8;
            int byteoff = l * 128 + ((w0 * 2) ^ ((l & 7) << 4));
            bf16x8 Af = *reinterpret_cast<const bf16x8*>(buf + byteoff);
            acc = __builtin_amdgcn_mfma_f32_32x32x16_bf16(Af, Bf[ks], acc, 0, 0, 0);
        }
        #pragma unroll
        for (int r = 0; r < 16; ++r) {
            int t = tt * 32 + (r & 3) + 8 * (r >> 2) + 4 * lhalf;
            bool valid = (tt < 3) || (t < LSEQ - 2);
            if (valid) dmax = fmaxf(dmax, acc[r]);
        }
    }
    dmax = fmaxf(dmax, __shfl_xor(dmax, 32));
    if (lhalf == 0 && dcol < DFILT)
        sent[n * DFILT + dcol] = tanhf(dmax + bcv);
}

// ---------------- kernel 1: 512 thr, 8 waves x 1 d-tile, T14 async-stage dbuf ------------
__global__ __launch_bounds__(512, 4) void pcnn_conv_sent(
    const int* __restrict__ x, const int* __restrict__ ld, const int* __restrict__ rd,
    const ushort_t* __restrict__ Wv64, const ushort_t* __restrict__ pf1b,
    const ushort_t* __restrict__ pf2b,
    const ushort_t* __restrict__ Bfrag, const float* __restrict__ bc,
    float* __restrict__ sent) {

    __shared__ __align__(16) unsigned char sembA[LROWS * 128];
    __shared__ __align__(16) unsigned char sembB[LROWS * 128];
    __shared__ int s_x[SPB * LSEQ];
    __shared__ int s_ld[SPB * LSEQ];
    __shared__ int s_rd[SPB * LSEQ];

    const int n0   = blockIdx.x * SPB;
    const int tid  = threadIdx.x;
    const int wv   = tid >> 6;
    const int lane = tid & 63;
    const int lhalf = lane >> 5;
    const int l31   = lane & 31;
    const int dcol  = wv * 32 + l31;

    // B fragments: this wave's single 32-wide d-tile
    bf16x8 Bf[KSTEPS];
    #pragma unroll
    for (int ks = 0; ks < KSTEPS; ++ks) {
        int c = ks * 2 + lhalf;
        Bf[ks] = *reinterpret_cast<const bf16x8*>(Bfrag + ((c * 256 + dcol) << 3));
    }
    const float bcv = (dcol < DFILT) ? bc[dcol] : 0.0f;

    // stage ids for all SPB sentences (960 ids, 512 threads -> strided loop)
    for (int i = tid; i < SPB * LSEQ; i += 512) {
        s_x[i]  = x[n0 * LSEQ + i];
        s_ld[i] = ld[n0 * LSEQ + i];
        s_rd[i] = rd[n0 * LSEQ + i];
    }
    // zero pad rows 120..129 of both buffers
    if (tid < 160) {
        int b = tid / 80, j = tid % 80;
        unsigned char* base = (b == 0 ? sembA : sembB) + 120 * 128;
        reinterpret_cast<uint4*>(base)[j] = uint4{0, 0, 0, 0};
    }
    __syncthreads();

    // prologue: stage sentence 0 into A
    uint4 stA, stB;
    stA = load_task(tid, s_x, s_ld, s_rd, Wv64, pf1b, pf2b);
    if (tid < 448) stB = load_task(tid + 512, s_x, s_ld, s_rd, Wv64, pf1b, pf2b);
    write_task(sembA, tid, stA);
    if (tid < 448) write_task(sembA, tid + 512, stB);
    __syncthreads();

    #pragma unroll
    for (int s = 0; s < SPB; ++s) {
        unsigned char* cur = (s & 1) ? sembB : sembA;
        unsigned char* nxt = (s & 1) ? sembA : sembB;
        // issue next sentence's global loads BEFORE compute (T14: latency hides under MFMA)
        if (s + 1 < SPB) {
            const int* sx  = s_x  + (s + 1) * LSEQ;
            const int* sl  = s_ld + (s + 1) * LSEQ;
            const int* sr  = s_rd + (s + 1) * LSEQ;
            stA = load_task(tid, sx, sl, sr, Wv64, pf1b, pf2b);
            if (tid < 448) stB = load_task(tid + 512, sx, sl, sr, Wv64, pf1b, pf2b);
        }
        conv_compute(cur, n0 + s, Bf, bcv, sent, dcol, lhalf, l31);
        __syncthreads();
        if (s + 1 < SPB) {
            write_task(nxt, tid, stA);
            if (tid < 448) write_task(nxt, tid + 512, stB);
        }
        __syncthreads();
    }
}

// ---------------- kernel 2: per-bag attention + scores + diag softmax ----------------
#define MAXNS 32
#define CPAD 56
__global__ __launch_bounds__(256) void pcnn_bag(
    const float* __restrict__ sent, const float* __restrict__ Wr, const float* __restrict__ br,
    const int* __restrict__ tshape, float* __restrict__ out) {

    __shared__ float s_sent[MAXNS * DFILT];
    __shared__ float s_Wr[NCLS * DFILT];
    __shared__ float s_e[MAXNS * CPAD];
    __shared__ float s_alpha[MAXNS * CPAD];
    __shared__ float s_sc[NCLS * NCLS];
    __shared__ float s_br[CPAD];

    const int g = blockIdx.x;
    const int tid = threadIdx.x;
    int start = tshape[g], end = tshape[g + 1];
    int ns = end - start;
    if (ns > MAXNS) ns = MAXNS;

    {
        int n2 = ns * (DFILT / 2);
        const float2* src = reinterpret_cast<const float2*>(sent + start * DFILT);
        for (int idx = tid; idx < n2; idx += 256)
            reinterpret_cast<float2*>(s_sent)[idx] = src[idx];
        const float2* wsrc = reinterpret_cast<const float2*>(Wr);
        for (int idx = tid; idx < (NCLS * DFILT) / 2; idx += 256)
            reinterpret_cast<float2*>(s_Wr)[idx] = wsrc[idx];
        if (tid < NCLS) s_br[tid] = br[tid];
    }
    __syncthreads();

    if (tid < 224) {
        int i0 = tid / 14, c0 = tid % 14;
        float a00 = 0, a01 = 0, a02 = 0, a03 = 0;
        float a10 = 0, a11 = 0, a12 = 0, a13 = 0;
        const float* s0p = s_sent + (2 * i0) * DFILT;
        const float* s1p = s_sent + (2 * i0 + 1) * DFILT;
        const float* w0p = s_Wr + (4 * c0 + 0) * DFILT;
        const float* w1p = s_Wr + (4 * c0 + 1) * DFILT;
        const float* w2p = (4 * c0 + 2 < NCLS) ? s_Wr + (4 * c0 + 2) * DFILT : s_Wr;
        const float* w3p = (4 * c0 + 3 < NCLS) ? s_Wr + (4 * c0 + 3) * DFILT : s_Wr;
        for (int d = 0; d < DFILT; ++d) {
            float s0 = s0p[d], s1 = s1p[d];
            float w0 = w0p[d], w1 = w1p[d], w2 = w2p[d], w3 = w3p[d];
            a00 = fmaf(s0, w0, a00); a01 = fmaf(s0, w1, a01);
            a02 = fmaf(s0, w2, a02); a03 = fmaf(s0, w3, a03);
            a10 = fmaf(s1, w0, a10); a11 = fmaf(s1, w1, a11);
            a12 = fmaf(s1, w2, a12); a13 = fmaf(s1, w3, a13);
        }
        float av[2][4] = {{a00, a01, a02, a03}, {a10, a11, a12, a13}};
        #pragma unroll
        for (int ii = 0; ii < 2; ++ii) {
            int i = 2 * i0 + ii;
            #pragma unroll
            for (int jj = 0; jj < 4; ++jj) {
                int c = 4 * c0 + jj;
                if (i < ns && c < NCLS) s_e[i * CPAD + c] = av[ii][jj] + s_br[c];
            }
        }
    }
    __syncthreads();

    if (tid < NCLS) {
        int c = tid;
        float m = -1e30f;
        for (int i = 0; i < ns; ++i) m = fmaxf(m, s_e[i * CPAD + c]);
        float den = 0.0f;
        for (int i = 0; i < ns; ++i) {
            float ex = expf(s_e[i * CPAD + c] - m);
            s_alpha[i * CPAD + c] = ex;
            den += ex;
        }
        float inv = 1.0f / den;
        for (int i = 0; i < ns; ++i) s_alpha[i * CPAD + c] *= inv;
    }
    __syncthreads();

    for (int task = tid; task < NCLS * 14; task += 256) {
        int c = task / 14, k0 = (task % 14) * 4;
        float b0 = s_br[k0], b1 = (k0+1<NCLS)?s_br[k0+1]:0.f, b2 = (k0+2<NCLS)?s_br[k0+2]:0.f, b3 = (k0+3<NCLS)?s_br[k0+3]:0.f;
        float a0 = 0, a1 = 0, a2 = 0, a3 = 0;
        for (int i = 0; i < ns; ++i) {
            float al = s_alpha[i * CPAD + c];
            const float* ep = s_e + i * CPAD + k0;
            a0 = fmaf(al, ep[0] - b0, a0);
            a1 = fmaf(al, (k0+1<NCLS?ep[1]:0.f) - b1, a1);
            a2 = fmaf(al, (k0+2<NCLS?ep[2]:0.f) - b2, a2);
            a3 = fmaf(al, (k0+3<NCLS?ep[3]:0.f) - b3, a3);
        }
        if (k0 + 0 < NCLS) s_sc[c * NCLS + k0 + 0] = a0 + b0;
        if (k0 + 1 < NCLS) s_sc[c * NCLS + k0 + 1] = a1 + b1;
        if (k0 + 2 < NCLS) s_sc[c * NCLS + k0 + 2] = a2 + b2;
        if (k0 + 3 < NCLS) s_sc[c * NCLS + k0 + 3] = a3 + b3;
    }
    __syncthreads();

    if (tid < NCLS) {
        int c = tid;
        float m = -1e30f;
        for (int k = 0; k < NCLS; ++k) m = fmaxf(m, s_sc[c * NCLS + k]);
        float den = 0.0f;
        for (int k = 0; k < NCLS; ++k) den += expf(s_sc[c * NCLS + k] - m);
        out[g * NCLS + c] = expf(s_sc[c * NCLS + c] - m) / den;
    }
}

extern "C" void kernel_launch(void* const* d_in, const int* in_sizes, int n_in,
                              void* d_out, int out_size, void* d_ws, size_t ws_size,
                              hipStream_t stream) {
    const int*   x   = (const int*)d_in[0];
    const int*   ldi = (const int*)d_in[1];
    const int*   rdi = (const int*)d_in[2];
    const int*   ts  = (const int*)d_in[3];
    const float* Wv  = (const float*)d_in[4];
    const float* pf1 = (const float*)d_in[5];
    const float* pf2 = (const float*)d_in[6];
    const float* Wc  = (const float*)d_in[7];
    const float* bc  = (const float*)d_in[8];
    const float* Wr  = (const float*)d_in[9];
    const float* br  = (const float*)d_in[10];
    float* out = (float*)d_out;

    char* ws = (char*)d_ws;
    ushort_t* Bfrag = (ushort_t*)(ws + OFF_BFRAG);
    ushort_t* Wv64  = (ushort_t*)(ws + OFF_WV64);
    ushort_t* pf1b  = (ushort_t*)(ws + OFF_PF1B);
    ushort_t* pf2b  = (ushort_t*)(ws + OFF_PF2B);
    float*    sent  = (float*)(ws + OFF_SENT);

    pcnn_prep_b<<<(BFRAG_ELEMS + 255) / 256, 256, 0, stream>>>(Wc, pf1, pf2, Bfrag, pf1b, pf2b);
    pcnn_prep_wv<<<(80000 * 64) / 256, 256, 0, stream>>>(Wv, Wv64);
    pcnn_conv_sent<<<NSENT / SPB, 512, 0, stream>>>(x, ldi, rdi, Wv64, pf1b, pf2b, Bfrag, bc, sent);
    pcnn_bag<<<GBAGS, 256, 0, stream>>>(sent, Wr, br, ts, out);
}